// Round 3
// baseline (537.343 us; speedup 1.0000x reference)
//
#include <hip/hip_runtime.h>

// AdaIN per-(batch,class) instance norm + style re-injection.
// B=4, C=64, H=W=512, K=19 classes.
//
// Pass structure:
//   memset(ws)            zero cnt + s1/s2 accumulators
//   count_kernel          labels -> cnt[76]            (4 MiB read)
//   stats_kernel          x -> s1,s2 per (b,k,c)       (256 MiB read, fills L3)
//   finalize_kernel       -> scale/bias[76][64] + small outputs
//   apply_kernel          out = fma(x, scale, bias)    (x re-read REVERSED for
//                         L3 reuse; out stored non-temporal to not evict x)

#define NCLS 19
#define BB 4
#define CC 64
#define HWPX 262144            // 512*512
#define NPLANES (BB * CC)      // 256
#define SEGS (BB * NCLS)       // 76
#define EPSV 1e-5f

// native vector type for nontemporal builtin (HIP float4 is a class type,
// which __builtin_nontemporal_store rejects)
typedef float nfloat4 __attribute__((ext_vector_type(4)));

// d_ws layout (zeroed each launch up to WS_ZERO_BYTES):
//   [0,   304)   cnt   int[76]            (padded to 512)
//   [512, 39424) s1s2  float2[76*64]      (s1, s2 interleaved)
//   [39424,78336) sb   float2[76*64]      (scale, bias) -- finalize overwrites
#define WS_S_OFF   512
#define WS_SB_OFF  39424
#define WS_ZERO_BYTES 39424

// ---------------------------------------------------------------- count ----
__global__ __launch_bounds__(256) void count_kernel(const int* __restrict__ y,
                                                    int* __restrict__ cnt) {
    __shared__ int acc[NCLS * 256];          // private slot per (class, thread)
    const int tid = threadIdx.x;
#pragma unroll
    for (int k = 0; k < NCLS; ++k) acc[k * 256 + tid] = 0;

    // 64 blocks x 16384 labels; 16 blocks per batch image
    const int b = blockIdx.x >> 4;
    const int4* y4 = (const int4*)y + (blockIdx.x * 16384) / 4;
#pragma unroll 4
    for (int i = 0; i < 16; ++i) {
        int4 l = y4[i * 256 + tid];
        acc[l.x * 256 + tid]++;
        acc[l.y * 256 + tid]++;
        acc[l.z * 256 + tid]++;
        acc[l.w * 256 + tid]++;
    }
    __syncthreads();
    const int lane = tid & 63;
    for (int k = 0; k < NCLS; ++k) {
        int v = acc[k * 256 + tid];
#pragma unroll
        for (int off = 32; off > 0; off >>= 1) v += __shfl_down(v, off, 64);
        if (lane == 0) atomicAdd(&cnt[b * NCLS + k], v);
    }
}

// ---------------------------------------------------------------- stats ----
// grid = 256 planes * 4 chunks; each block: one (b,c) plane chunk of 65536 px.
// Private-LDS-slot accumulation: acc[class][tid], no atomics in hot loop.
// Bank pattern: addr = (k*256+tid)*8 -> bank depends on tid only, uniform.
__global__ __launch_bounds__(256) void stats_kernel(const float* __restrict__ x,
                                                    const int* __restrict__ y,
                                                    float* __restrict__ s1s2) {
    __shared__ float2 acc[NCLS * 256];       // 38912 B
    const int tid = threadIdx.x;
#pragma unroll
    for (int k = 0; k < NCLS; ++k) acc[k * 256 + tid] = make_float2(0.f, 0.f);

    const int plane = blockIdx.x >> 2;
    const int chunk = blockIdx.x & 3;
    const int b = plane >> 6;
    const int c = plane & 63;

    const float4* x4 = (const float4*)(x + (size_t)plane * HWPX + chunk * 65536);
    const int4*  y4 = (const int4*) (y + (size_t)b     * HWPX + chunk * 65536);

#pragma unroll 4
    for (int i = 0; i < 64; ++i) {
        float4 v = x4[i * 256 + tid];
        int4   l = y4[i * 256 + tid];
        float2 a;
        a = acc[l.x * 256 + tid]; a.x += v.x; a.y += v.x * v.x; acc[l.x * 256 + tid] = a;
        a = acc[l.y * 256 + tid]; a.x += v.y; a.y += v.y * v.y; acc[l.y * 256 + tid] = a;
        a = acc[l.z * 256 + tid]; a.x += v.z; a.y += v.z * v.z; acc[l.z * 256 + tid] = a;
        a = acc[l.w * 256 + tid]; a.x += v.w; a.y += v.w * v.w; acc[l.w * 256 + tid] = a;
    }
    __syncthreads();

    const int lane = tid & 63;
    for (int k = 0; k < NCLS; ++k) {
        float2 v = acc[k * 256 + tid];
#pragma unroll
        for (int off = 32; off > 0; off >>= 1) {
            v.x += __shfl_down(v.x, off, 64);
            v.y += __shfl_down(v.y, off, 64);
        }
        if (lane == 0) {
            const int idx = ((b * NCLS + k) * 64 + c) * 2;
            atomicAdd(&s1s2[idx],     v.x);
            atomicAdd(&s1s2[idx + 1], v.y);
        }
    }
}

// ------------------------------------------------------------- finalize ----
// grid = 76 segs, block = 64 channels.
__global__ __launch_bounds__(64) void finalize_kernel(
        const float* __restrict__ s1s2, const int* __restrict__ cnt,
        const float* __restrict__ style_means, const float* __restrict__ style_stds,
        float2* __restrict__ sb, float* __restrict__ out_sm,
        float* __restrict__ out_ss, float* __restrict__ out_valid) {
    const int seg = blockIdx.x;
    const int k = seg % NCLS;
    const int c = threadIdx.x;

    const float n = (float)cnt[seg];
    const bool valid = n > 6.0f;                 // cnt > COUNT
    const float cs = fmaxf(n, 1.0f);             // reference's cnt_safe
    const float s1 = s1s2[(seg * 64 + c) * 2];
    const float s2 = s1s2[(seg * 64 + c) * 2 + 1];
    const float mean = s1 / cs;
    const float var = (s2 - cs * mean * mean) / fmaxf(n - 1.0f, 1.0f);  // unbiased
    const float sd = sqrtf(fmaxf(var, 0.0f)) + EPSV;   // eps on content std only
    const float sm = style_means[k * 64 + c];
    const float ss = style_stds[k * 64 + c];

    float scale = 1.0f, bias = 0.0f;             // invalid -> out = x
    if (valid) { scale = ss / sd; bias = fmaf(-mean, scale, sm); }

    sb[seg * 64 + c] = make_float2(scale, bias);
    out_sm[seg * 64 + c] = valid ? sm : 0.0f;
    out_ss[seg * 64 + c] = valid ? ss : 0.0f;
    if (c == 0) out_valid[seg] = valid ? 1.0f : 0.0f;
}

// ---------------------------------------------------------------- apply ----
// grid = 256 planes * 8 chunks, traversed in REVERSE global order so the tail
// of x (most recently L3-resident after stats) is re-read first. out stores
// are non-temporal so the 256 MiB of writes don't evict x from L3.
__global__ __launch_bounds__(256) void apply_kernel(const float* __restrict__ x,
                                                    const int* __restrict__ y,
                                                    const float2* __restrict__ sb,
                                                    float* __restrict__ out) {
    __shared__ float2 sbl[NCLS];
    const int tid = threadIdx.x;
    const int gb = (NPLANES * 8 - 1) - blockIdx.x;   // reversed traversal
    const int plane = gb >> 3;
    const int chunk = gb & 7;
    const int b = plane >> 6;
    const int c = plane & 63;
    if (tid < NCLS) sbl[tid] = sb[(b * NCLS + tid) * 64 + c];
    __syncthreads();

    const size_t base = (size_t)plane * HWPX + chunk * 32768;
    const float4* x4 = (const float4*)(x + base);
    const int4*  y4 = (const int4*)(y + (size_t)b * HWPX + chunk * 32768);
    nfloat4* o4 = (nfloat4*)(out + base);

#pragma unroll 4
    for (int i = 0; i < 32; ++i) {
        float4 v = x4[i * 256 + tid];
        int4   l = y4[i * 256 + tid];
        float2 s0 = sbl[l.x], s1 = sbl[l.y], s2 = sbl[l.z], s3 = sbl[l.w];
        nfloat4 r;
        r.x = fmaf(v.x, s0.x, s0.y);
        r.y = fmaf(v.y, s1.x, s1.y);
        r.z = fmaf(v.z, s2.x, s2.y);
        r.w = fmaf(v.w, s3.x, s3.y);
        __builtin_nontemporal_store(r, &o4[i * 256 + tid]);
    }
}

// --------------------------------------------------------------- launch ----
extern "C" void kernel_launch(void* const* d_in, const int* in_sizes, int n_in,
                              void* d_out, int out_size, void* d_ws, size_t ws_size,
                              hipStream_t stream) {
    const float* x           = (const float*)d_in[0];
    const int*   y           = (const int*)  d_in[1];
    const float* style_means = (const float*)d_in[2];
    const float* style_stds  = (const float*)d_in[3];
    float* out = (float*)d_out;

    int*    cnt  = (int*)d_ws;
    float*  s1s2 = (float*)((char*)d_ws + WS_S_OFF);
    float2* sb   = (float2*)((char*)d_ws + WS_SB_OFF);

    // output tuple layout (flat, return order)
    float* out_main  = out;                       // [4,64,512,512]
    float* out_sm    = out + 67108864;            // [4,19,64]
    float* out_ss    = out + 67113728;            // [4,19,64]
    float* out_valid = out + 67118592;            // [4,19]

    (void)hipMemsetAsync(d_ws, 0, WS_ZERO_BYTES, stream);

    count_kernel   <<<64, 256, 0, stream>>>(y, cnt);
    stats_kernel   <<<NPLANES * 4, 256, 0, stream>>>(x, y, s1s2);
    finalize_kernel<<<SEGS, 64, 0, stream>>>(s1s2, cnt, style_means, style_stds,
                                             sb, out_sm, out_ss, out_valid);
    apply_kernel   <<<NPLANES * 8, 256, 0, stream>>>(x, y, sb, out_main);
}